// Round 26
// baseline (323.904 us; speedup 1.0000x reference)
//
#include <hip/hip_runtime.h>
#include <hip/hip_bf16.h>

typedef __attribute__((ext_vector_type(8))) short bfrag8;
typedef __attribute__((ext_vector_type(4))) float f32x4;
typedef __attribute__((ext_vector_type(4))) unsigned int u32x4;

#define IS2_SCALE 0.84932180028801907f   /* sqrt(0.5*log2(e)): exp2(-(u)^2)=exp(-t^2/2) */
#define W1_SCALE  0.46971724f            /* folds 1/(sqrt(2pi)*std) into W1 via is2 */

#if __has_builtin(__builtin_amdgcn_exp2f)
#define GEXP(x) __builtin_amdgcn_exp2f(x)
#else
__device__ __forceinline__ float gexp_asm(float x) {
  float r; asm("v_exp_f32 %0, %1" : "=v"(r) : "v"(x)); return r;
}
#define GEXP(x) gexp_asm(x)
#endif

__device__ __forceinline__ unsigned short f2bf(float x) {
  union { float f; unsigned u; } v; v.f = x;
  unsigned r = v.u + 0x7fffu + ((v.u >> 16) & 1u);
  return (unsigned short)(r >> 16);
}
__device__ __forceinline__ unsigned cvtpk(float lo, float hi) {
  unsigned r;
  asm("v_cvt_pk_bf16_f32 %0, %1, %2" : "=v"(r) : "v"(lo), "v"(hi));
  return r;
}
__device__ __forceinline__ float rcpa(float x) {
  float r; asm("v_rcp_f32 %0, %1" : "=v"(r) : "v"(x)); return r;
}
// tanh-form GELU: x/(1+exp2(x*(C0+C1*x^2)))
__device__ __forceinline__ float gelu_fast(float x) {
  float x2 = x * x;
  float w = __builtin_fmaf(x2, -0.1029488f, -2.3022078f);
  float e = GEXP(x * w);
  return x * rcpa(e + 1.0f);
}

// SINGLE A-fragment (one 16-row group, 8 gaussians) for K-block kb
__device__ __forceinline__ bfrag8 gauss_frag(const f32x4* prm4, const f32x4 x4,
                                             int kb, int lg) {
  const int k0 = kb * 32 + lg * 8;
  const float x0 = x4[kb >> 2];
  unsigned pk[4];
#pragma unroll
  for (int q = 0; q < 4; ++q) {
    f32x4 P = prm4[(k0 >> 1) + q];     // {mis2_e, is2_e, mis2_o, is2_o}
    float u0 = __builtin_fmaf(x0, P[1], P[0]);
    float u1 = __builtin_fmaf(x0, P[3], P[2]);
    pk[q] = cvtpk(P[1] * GEXP(-(u0 * u0)), P[3] * GEXP(-(u1 * u1)));
  }
  u32x4 av = {pk[0], pk[1], pk[2], pk[3]};
  return __builtin_bit_cast(bfrag8, av);
}

// ---------------- prep: weights->bf16 (W1 pre-scaled), packed gaussian params -
// W2 stored k-PERMUTED (R25): permuted pos t in each 32-col group holds real
// col (t&1)*16 + (t>>1), matching the paired h-write layout.
__global__ void prep_kernel(const float* __restrict__ means, const float* __restrict__ stds,
                            const float* __restrict__ W1, const float* __restrict__ W2,
                            unsigned short* __restrict__ W1bf, unsigned short* __restrict__ W2bf,
                            float* __restrict__ prm /* [512][2]: mis2, is2 */) {
  int t = blockIdx.x * blockDim.x + threadIdx.x;
  int stride = gridDim.x * blockDim.x;
  for (int i = t; i < 512 * 512; i += stride) W1bf[i] = f2bf(W1[i] * W1_SCALE);
  for (int i = t; i < 32 * 512; i += stride) {
    int q = i & 511;
    int c = (q & ~31) | ((q & 1) << 4) | ((q & 31) >> 1);   // inverse permutation
    W2bf[i] = f2bf(W2[(i & ~511) | c]);
  }
  for (int i = t; i < 512; i += stride) {
    float s = fabsf(stds[i]) + 0.01f;
    float is2 = (1.0f / s) * IS2_SCALE;
    prm[2 * i] = -means[i] * is2;        // mis2
    prm[2 * i + 1] = is2;                // is2  (coef folded into W1)
  }
}

// ---------------- fused main kernel ------------------------------------------
// BM=64, 512 threads = 8 waves (2M x 4N), 79KB LDS -> TWO blocks per CU so one
// block's epilogue/prologue overlaps the other's K-loop. Double-buffered B with
// ONE barrier/kb (stage-after-barrier targets the buffer read last iter); 4
// producer waves (w=0,2,5,7 -> one per SIMD) each compute ONE A-frag/kb into a
// 2-slot gsl read just after the next barrier (R14 placement). Paired permuted
// h-writes (R25) + permuted W2.
__global__ __launch_bounds__(512, 4) void fused_kernel(
    const float* __restrict__ rpe, const unsigned short* __restrict__ W1bf,
    const unsigned short* __restrict__ W2bf, const float* __restrict__ prm,
    const float* __restrict__ b1, const float* __restrict__ b2,
    float* __restrict__ out) {
  __shared__ __attribute__((aligned(16))) char lds[65536 + 8192 + 4096 + 1024 + 2048];
  // [0,64K): B dbuf 2x32KB; h[64][512] bf16 overlays; ob[64][33] f32 overlays
  char*  gsl   = lds + 65536;                       // [2slot][2mw][2fr][4lg][16lr]x16B = 8KB
  float* prm_s = (float*)(lds + 65536 + 8192);      // 4KB
  float* rpe_s = (float*)(lds + 65536 + 8192 + 4096);        // [64][4] 1KB
  float* b1_s  = (float*)(lds + 65536 + 8192 + 4096 + 1024); // 2KB

  const int tid = threadIdx.x;
  const int rb = blockIdx.x * 64;

  if (tid < 256) rpe_s[tid] = rpe[rb * 4 + tid];
  for (int i = tid; i < 1024; i += 512) prm_s[i] = prm[i];
  b1_s[tid] = b1[tid];

  int goff[4];
#pragma unroll
  for (int i = 0; i < 4; ++i) {
    int c = i * 512 + tid;
    int j = ((c >> 6) << 4) + (c & 15);
    goff[i] = j * 512 + ((c >> 4) & 3) * 8;
  }
  const char* Wc = (const char*)W1bf;

#define STAGE(buf, kb)                                                          \
  {                                                                             \
    _Pragma("unroll") for (int i_ = 0; i_ < 4; ++i_) {                          \
      const void* gp = (const void*)(Wc + (size_t)goff[i_] * 2 + (kb) * 64);    \
      void* lp = (void*)(lds + (buf) * 32768 + i_ * 8192 + tid * 16);           \
      __builtin_amdgcn_global_load_lds(                                         \
          (const __attribute__((address_space(1))) void*)gp,                    \
          (__attribute__((address_space(3))) void*)lp, 16, 0, 0);               \
    }                                                                           \
  }

  STAGE(0, 0);
  __syncthreads();   // params + B buf0 collectively ready (full drain)

  const int w = tid >> 6, l = tid & 63;
  const int lr = l & 15, lg = l >> 4;
  const int mw = w >> 2, nw = w & 3;     // 2 M-waves x 4 N-waves (32r x 128c tile)
  const bool prod = (w == 0) | (w == 2) | (w == 5) | (w == 7);  // SIMDs 0,2,1,3
  const int pmw = (w == 0 || w == 5) ? 0 : 1;
  const int pfr = (w == 0 || w == 2) ? 0 : 1;

  const f32x4* prm4 = (const f32x4*)prm_s;
  const f32x4 xp = *(const f32x4*)&rpe_s[(pmw * 32 + pfr * 16 + lr) * 4];  // producer rows

  char* gwr = gsl + pmw * 2048 + pfr * 1024 + lg * 256 + lr * 16;   // + slot*4096
  const char* grd = gsl + mw * 2048 + lg * 256 + lr * 16;           // frags (mw,0),(mw,1)

  // ---- prologue: producers fill slot 0
  if (prod) *(bfrag8*)(gwr) = gauss_frag(prm4, xp, 0, lg);
  __syncthreads();   // slot 0 visible

  f32x4 zv = {0.f, 0.f, 0.f, 0.f};
  f32x4 acc[2][8];
#pragma unroll
  for (int mf = 0; mf < 2; ++mf)
#pragma unroll
    for (int nf = 0; nf < 8; ++nf) acc[mf][nf] = zv;

  bfrag8 fA[4], fB[4];

#pragma unroll
  for (int kb = 0; kb < 16; ++kb) {
    // certify stage(kb) issued last iter (buf kb&1); rendezvous
    asm volatile("s_waitcnt vmcnt(0)" ::: "memory");
    __builtin_amdgcn_s_barrier();
    __builtin_amdgcn_sched_barrier(0);
    if (kb < 15) STAGE((kb + 1) & 1, kb + 1);

    // ---- A frags from slot kb&1 (written iter kb-1, drained pre-barrier)
    const char* gs = grd + (kb & 1) * 4096;
    bfrag8 acur0 = *(const bfrag8*)(gs);
    bfrag8 acur1 = *(const bfrag8*)(gs + 1024);

    // ---- B frags from buf kb&1; half-split issue
    const char* Bb = lds + (kb & 1) * 32768 + nw * 8192 + lg * 256 + lr * 16;
    __builtin_amdgcn_s_setprio(1);
#pragma unroll
    for (int nf = 0; nf < 4; ++nf) fA[nf] = *(const bfrag8*)(Bb + nf * 1024);
#pragma unroll
    for (int nf = 0; nf < 4; ++nf) fB[nf] = *(const bfrag8*)(Bb + (nf + 4) * 1024);
#pragma unroll
    for (int nf = 0; nf < 4; ++nf) {
      acc[0][nf] = __builtin_amdgcn_mfma_f32_16x16x32_bf16(acur0, fA[nf], acc[0][nf], 0, 0, 0);
      acc[1][nf] = __builtin_amdgcn_mfma_f32_16x16x32_bf16(acur1, fA[nf], acc[1][nf], 0, 0, 0);
    }
#pragma unroll
    for (int nf = 0; nf < 4; ++nf) {
      acc[0][nf + 4] = __builtin_amdgcn_mfma_f32_16x16x32_bf16(acur0, fB[nf], acc[0][nf + 4], 0, 0, 0);
      acc[1][nf + 4] = __builtin_amdgcn_mfma_f32_16x16x32_bf16(acur1, fB[nf], acc[1][nf + 4], 0, 0, 0);
    }
    __builtin_amdgcn_s_setprio(0);

    // ---- producer: gauss(kb+1) -> slot (kb+1)&1, drained before next barrier
    if (prod && kb < 15) {
      *(bfrag8*)(gwr + ((kb + 1) & 1) * 4096) = gauss_frag(prm4, xp, kb + 1, lg);
      asm volatile("s_waitcnt lgkmcnt(0)" ::: "memory");
    }
    __builtin_amdgcn_sched_barrier(0);
  }
  __syncthreads();   // all B/gsl reads done -> safe to overlay h

  // ---- bias + fast GELU -> h[64][512-permuted] bf16, paired b32 writes
  unsigned short* hbuf = (unsigned short*)lds;
#pragma unroll
  for (int mf = 0; mf < 2; ++mf) {
#pragma unroll
    for (int j = 0; j < 4; ++j) {
      int col0 = nw * 128 + j * 32 + lr;
      int col1 = col0 + 16;
      float bb0 = b1_s[col0], bb1 = b1_s[col1];
      int qb = nw * 256 + j * 64 + lr * 4;
#pragma unroll
      for (int bi = 0; bi < 4; ++bi) {
        float g0 = gelu_fast(acc[mf][2 * j][bi] + bb0);
        float g1 = gelu_fast(acc[mf][2 * j + 1][bi] + bb1);
        unsigned pr = cvtpk(g0, g1);
        int hrow = mw * 32 + mf * 16 + lg * 4 + bi;
        *(unsigned*)((char*)hbuf + hrow * 1024 + (qb ^ ((hrow & 7) << 4))) = pr;
      }
    }
  }
  __syncthreads();

  // ---- GEMM2: out[64][32] = h @ W2perm^T. 8 waves: 4(row) x 2(col) tiles.
  const int rt = w >> 1, ct = w & 1;
  f32x4 acc2 = zv;
  const int row2 = rt * 16 + lr;
  for (int kb = 0; kb < 16; ++kb) {
    int cb = (kb * 64 + lg * 16) ^ ((row2 & 7) << 4);
    bfrag8 a = *(const bfrag8*)((char*)hbuf + row2 * 1024 + cb);
    bfrag8 b = *(const bfrag8*)(W2bf + (size_t)(ct * 16 + lr) * 512 + kb * 32 + lg * 8);
    acc2 = __builtin_amdgcn_mfma_f32_16x16x32_bf16(a, b, acc2, 0, 0, 0);
  }
  float b2v = b2[ct * 16 + lr];
  __syncthreads();                     // all h reads done -> safe to overlay

  float* ob = (float*)lds;             // [64][33] padded f32
#pragma unroll
  for (int bi = 0; bi < 4; ++bi)
    ob[(rt * 16 + lg * 4 + bi) * 33 + (ct * 16 + lr)] = acc2[bi] + b2v;
  __syncthreads();

  // ---- store transposed: out[b][o][m][n], 64 contiguous n per head
  const int bI = rb >> 16, mI = (rb >> 8) & 255, n0 = rb & 255;
  float* obase = out + ((size_t)(bI * 32) * 256 + mI) * 256 + n0;
#pragma unroll
  for (int p = 0; p < 4; ++p) {
    int e = tid + p * 512;             // 0..2047
    int o = e >> 6, i = e & 63;
    obase[(size_t)o * 65536 + i] = ob[i * 33 + o];
  }
#undef STAGE
}

// ---------------- launch ------------------------------------------------------
extern "C" void kernel_launch(void* const* d_in, const int* in_sizes, int n_in,
                              void* d_out, int out_size, void* d_ws, size_t ws_size,
                              hipStream_t stream) {
  const float* rpe   = (const float*)d_in[0];
  const float* means = (const float*)d_in[1];
  const float* stds  = (const float*)d_in[2];
  const float* W1    = (const float*)d_in[3];
  const float* b1    = (const float*)d_in[4];
  const float* W2    = (const float*)d_in[5];
  const float* b2    = (const float*)d_in[6];
  float* out = (float*)d_out;

  char* ws = (char*)d_ws;
  unsigned short* W1bf = (unsigned short*)ws;             // 512*512*2 = 524288 B
  unsigned short* W2bf = (unsigned short*)(ws + 524288);  // 32*512*2  =  32768 B
  float* prm = (float*)(ws + 557056);                     // 512*2*4   =   4096 B

  prep_kernel<<<256, 256, 0, stream>>>(means, stds, W1, W2, W1bf, W2bf, prm);
  fused_kernel<<<4096, 512, 0, stream>>>(rpe, W1bf, W2bf, prm, b1, b2, out);
}

// Round 28
// 254.375 us; speedup vs baseline: 1.2733x; 1.2733x over previous
//
#include <hip/hip_runtime.h>
#include <hip/hip_bf16.h>

typedef __attribute__((ext_vector_type(8))) short bfrag8;
typedef __attribute__((ext_vector_type(4))) float f32x4;
typedef __attribute__((ext_vector_type(4))) unsigned int u32x4;

#define IS2_SCALE 0.84932180028801907f   /* sqrt(0.5*log2(e)): exp2(-(u)^2)=exp(-t^2/2) */
#define W1_SCALE  0.46971724f            /* folds 1/(sqrt(2pi)*std) into W1 via is2 */

#if __has_builtin(__builtin_amdgcn_exp2f)
#define GEXP(x) __builtin_amdgcn_exp2f(x)
#else
__device__ __forceinline__ float gexp_asm(float x) {
  float r; asm("v_exp_f32 %0, %1" : "=v"(r) : "v"(x)); return r;
}
#define GEXP(x) gexp_asm(x)
#endif

__device__ __forceinline__ unsigned short f2bf(float x) {
  union { float f; unsigned u; } v; v.f = x;
  unsigned r = v.u + 0x7fffu + ((v.u >> 16) & 1u);
  return (unsigned short)(r >> 16);
}
__device__ __forceinline__ unsigned cvtpk(float lo, float hi) {
  unsigned r;
  asm("v_cvt_pk_bf16_f32 %0, %1, %2" : "=v"(r) : "v"(lo), "v"(hi));
  return r;
}
__device__ __forceinline__ float rcpa(float x) {
  float r; asm("v_rcp_f32 %0, %1" : "=v"(r) : "v"(x)); return r;
}
// tanh-form GELU: x/(1+exp2(x*(C0+C1*x^2)))
__device__ __forceinline__ float gelu_fast(float x) {
  float x2 = x * x;
  float w = __builtin_fmaf(x2, -0.1029488f, -2.3022078f);
  float e = GEXP(x * w);
  return x * rcpa(e + 1.0f);
}

// A-fragment pair (rows r0, r0+16) for K-block kb: 16 gaussians
__device__ __forceinline__ void gauss_frags(const f32x4* prm4, const f32x4 xa, const f32x4 xb,
                                            int kb, int lg, bfrag8* A0, bfrag8* A1) {
  const int k0 = kb * 32 + lg * 8;
  const float x0 = xa[kb >> 2], x1 = xb[kb >> 2];
  unsigned pk0[4], pk1[4];
#pragma unroll
  for (int q = 0; q < 4; ++q) {
    f32x4 P = prm4[(k0 >> 1) + q];     // {mis2_e, is2_e, mis2_o, is2_o}
    float u00 = __builtin_fmaf(x0, P[1], P[0]);
    float u01 = __builtin_fmaf(x0, P[3], P[2]);
    float u10 = __builtin_fmaf(x1, P[1], P[0]);
    float u11 = __builtin_fmaf(x1, P[3], P[2]);
    pk0[q] = cvtpk(P[1] * GEXP(-(u00 * u00)), P[3] * GEXP(-(u01 * u01)));
    pk1[q] = cvtpk(P[1] * GEXP(-(u10 * u10)), P[3] * GEXP(-(u11 * u11)));
  }
  u32x4 av0 = {pk0[0], pk0[1], pk0[2], pk0[3]};
  u32x4 av1 = {pk1[0], pk1[1], pk1[2], pk1[3]};
  *A0 = __builtin_bit_cast(bfrag8, av0);
  *A1 = __builtin_bit_cast(bfrag8, av1);
}

// ---------------- prep: weights->bf16 (W1 pre-scaled), packed gaussian params -
// W2 is stored k-PERMUTED: within each 32-col group, permuted pos t holds real
// col (t&1)*16 + (t>>1). Matches the fused kernel's paired h-write layout
// (pair (c, c+16) stored adjacently); GEMM2 contracts in permuted order.
__global__ void prep_kernel(const float* __restrict__ means, const float* __restrict__ stds,
                            const float* __restrict__ W1, const float* __restrict__ W2,
                            unsigned short* __restrict__ W1bf, unsigned short* __restrict__ W2bf,
                            float* __restrict__ prm /* [512][2]: mis2, is2 */) {
  int t = blockIdx.x * blockDim.x + threadIdx.x;
  int stride = gridDim.x * blockDim.x;
  for (int i = t; i < 512 * 512; i += stride) W1bf[i] = f2bf(W1[i] * W1_SCALE);
  for (int i = t; i < 32 * 512; i += stride) {
    int q = i & 511;
    int c = (q & ~31) | ((q & 1) << 4) | ((q & 31) >> 1);   // inverse permutation
    W2bf[i] = f2bf(W2[(i & ~511) | c]);
  }
  for (int i = t; i < 512; i += stride) {
    float s = fabsf(stds[i]) + 0.01f;
    float is2 = (1.0f / s) * IS2_SCALE;
    prm[2 * i] = -means[i] * is2;        // mis2
    prm[2 * i + 1] = is2;                // is2  (coef folded into W1)
  }
}

// ---------------- fused main kernel ------------------------------------------
// 1024 threads = 16 waves (4M x 4N), 128 rows/block, BK=32, triple-buffered B,
// ONE barrier per kb, half-split pipeline, per-SIMD gaussian producer waves
// (R18 base). h stored k-PERMUTED so each cvtpk pair is one aligned
// ds_write_b32; W2bf pre-permuted to match. NOTE: vmcnt(0) before the barrier
// is REQUIRED — it certifies buffer kb+1 collectively, which the hf1
// read-ahead depends on (counted vmcnt races it: R27 NaN).
// (R25 — best measured: 255.1 us.)
__global__ __launch_bounds__(1024, 4) void fused_kernel(
    const float* __restrict__ rpe, const unsigned short* __restrict__ W1bf,
    const unsigned short* __restrict__ W2bf, const float* __restrict__ prm,
    const float* __restrict__ b1, const float* __restrict__ b2,
    float* __restrict__ out) {
  __shared__ __attribute__((aligned(16))) char lds[131072 + 4096 + 2048 + 2048];
  // [0,96K): 3x32KB B buffers; [96K,120K): gsl 3x8KB; h[128][512] overlays [0,128K)
  char*  gsl   = lds + 98304;                             // [3][4mw][2fr][4lg][16lr]x16B
  float* prm_s = (float*)(lds + 131072);                  // [512][2] = 4KB
  float* rpe_s = (float*)(lds + 131072 + 4096);           // [128][4] = 2KB
  float* b1_s  = (float*)(lds + 131072 + 4096 + 2048);    // [512]    = 2KB

  const int tid = threadIdx.x;
  const int rb = blockIdx.x * 128;

  if (tid < 512) rpe_s[tid] = rpe[rb * 4 + tid];
  prm_s[tid] = prm[tid];                 // 1024 floats
  if (tid < 512) b1_s[tid] = b1[tid];

  int goff[2];
#pragma unroll
  for (int i = 0; i < 2; ++i) {
    int c = i * 1024 + tid;
    int j = ((c >> 6) << 4) + (c & 15);
    goff[i] = j * 512 + ((c >> 4) & 3) * 8;
  }
  const char* Wc = (const char*)W1bf;

#define STAGE(buf, kb)                                                          \
  {                                                                             \
    _Pragma("unroll") for (int i_ = 0; i_ < 2; ++i_) {                          \
      const void* gp = (const void*)(Wc + (size_t)goff[i_] * 2 + (kb) * 64);    \
      void* lp = (void*)(lds + (buf) * 32768 + i_ * 16384 + tid * 16);          \
      __builtin_amdgcn_global_load_lds(                                         \
          (const __attribute__((address_space(1))) void*)gp,                    \
          (__attribute__((address_space(3))) void*)lp, 16, 0, 0);               \
    }                                                                           \
  }

  STAGE(0, 0);
  STAGE(1, 1);

  const int w = tid >> 6, l = tid & 63;
  const int lr = l & 15, lg = l >> 4;
  const int mw = w >> 2, nw = w & 3;     // 4 M-waves x 4 N-waves
  const int r0 = mw * 32 + lr;           // A rows r0 and r0+16
  const bool prod = (mw == nw);          // waves 0,5,10,15 -> one per SIMD

  const f32x4 xa = *(const f32x4*)&rpe_s[r0 * 4];
  const f32x4 xb = *(const f32x4*)&rpe_s[(r0 + 16) * 4];
  const f32x4* prm4 = (const f32x4*)prm_s;

  char* gbase = gsl + mw * 2048 + lg * 256 + lr * 16;   // + slot*8192, frag1 +1024

  __syncthreads();   // rpe/prm/b1 staged (needed by producers below); B 0,1 in flight

  // ---- prologue: producers fill slots 0,1
  if (prod) {
    bfrag8 t0, t1;
    gauss_frags(prm4, xa, xb, 0, lg, &t0, &t1);
    *(bfrag8*)(gbase) = t0;  *(bfrag8*)(gbase + 1024) = t1;
    gauss_frags(prm4, xa, xb, 1, lg, &t0, &t1);
    *(bfrag8*)(gbase + 8192) = t0;  *(bfrag8*)(gbase + 8192 + 1024) = t1;
  }
  __syncthreads();   // gsl slots 0,1 visible; B slices 0,1 drained (vmcnt in syncthreads)

  f32x4 zv = {0.f, 0.f, 0.f, 0.f};
  f32x4 acc[2][8];
#pragma unroll
  for (int mf = 0; mf < 2; ++mf)
#pragma unroll
    for (int nf = 0; nf < 8; ++nf) acc[mf][nf] = zv;

  // ---- pre-read A(0) + B(0, half0)
  bfrag8 acur0 = *(const bfrag8*)(gbase);
  bfrag8 acur1 = *(const bfrag8*)(gbase + 1024);
  bfrag8 fA[4], fB[4];
  {
    const char* Bb = lds + nw * 8192 + lg * 256 + lr * 16;
#pragma unroll
    for (int nf = 0; nf < 4; ++nf) fA[nf] = *(const bfrag8*)(Bb + nf * 1024);
  }

#pragma unroll
  for (int kb = 0; kb < 16; ++kb) {
    // certify buf(kb+1) (stage issued iter kb-1) + gsl slot(kb+1) writes.
    // vmcnt(0) is REQUIRED here (hf1 read-ahead depends on buf kb+1 complete).
    asm volatile("s_waitcnt vmcnt(0)" ::: "memory");
    __builtin_amdgcn_s_barrier();
    __builtin_amdgcn_sched_barrier(0);
    if (kb < 14) STAGE((kb + 2) % 3, kb + 2);

    // ---- hf0: issue reads half1, MFMA half0
    const char* Bb = lds + (kb % 3) * 32768 + nw * 8192 + lg * 256 + lr * 16;
    __builtin_amdgcn_s_setprio(1);
#pragma unroll
    for (int nf = 0; nf < 4; ++nf) fB[nf] = *(const bfrag8*)(Bb + (nf + 4) * 1024);
#pragma unroll
    for (int nf = 0; nf < 4; ++nf) {
      acc[0][nf] = __builtin_amdgcn_mfma_f32_16x16x32_bf16(acur0, fA[nf], acc[0][nf], 0, 0, 0);
      acc[1][nf] = __builtin_amdgcn_mfma_f32_16x16x32_bf16(acur1, fA[nf], acc[1][nf], 0, 0, 0);
    }
    __builtin_amdgcn_s_setprio(0);
    __builtin_amdgcn_sched_barrier(0);

    // ---- hf1: read-ahead B(kb+1, half0), MFMA half1
    __builtin_amdgcn_s_setprio(1);
    if (kb < 15) {
      const char* Bn = lds + ((kb + 1) % 3) * 32768 + nw * 8192 + lg * 256 + lr * 16;
#pragma unroll
      for (int nf = 0; nf < 4; ++nf) fA[nf] = *(const bfrag8*)(Bn + nf * 1024);
    }
#pragma unroll
    for (int nf = 0; nf < 4; ++nf) {
      acc[0][nf + 4] = __builtin_amdgcn_mfma_f32_16x16x32_bf16(acur0, fB[nf], acc[0][nf + 4], 0, 0, 0);
      acc[1][nf + 4] = __builtin_amdgcn_mfma_f32_16x16x32_bf16(acur1, fB[nf], acc[1][nf + 4], 0, 0, 0);
    }
    __builtin_amdgcn_s_setprio(0);

    // ---- A pipeline: read a(kb+1) from slot (kb+1)%3 (written iter kb-1)
    if (kb < 15) {
      const char* gs = gbase + ((kb + 1) % 3) * 8192;
      acur0 = *(const bfrag8*)(gs);
      acur1 = *(const bfrag8*)(gs + 1024);
    }
    // ---- producer: gauss(kb+2) -> slot (kb+2)%3, drained before next barrier
    if (prod && kb < 14) {
      bfrag8 t0, t1;
      gauss_frags(prm4, xa, xb, kb + 2, lg, &t0, &t1);
      char* gd = gbase + ((kb + 2) % 3) * 8192;
      *(bfrag8*)(gd) = t0;  *(bfrag8*)(gd + 1024) = t1;
      asm volatile("s_waitcnt lgkmcnt(0)" ::: "memory");
    }
    __builtin_amdgcn_sched_barrier(0);
  }
  __syncthreads();   // all B/gsl reads done -> safe to overlay h

  // ---- bias + fast GELU -> h in LDS [128][512-permuted] bf16, XOR-swizzled,
  //      one aligned b32 write per cvtpk pair (cols c, c+16 adjacent under pi)
  unsigned short* hbuf = (unsigned short*)lds;
#pragma unroll
  for (int mf = 0; mf < 2; ++mf) {
#pragma unroll
    for (int j = 0; j < 4; ++j) {        // nf pair (2j, 2j+1)
      int col0 = nw * 128 + j * 32 + lr;
      int col1 = col0 + 16;
      float bb0 = b1_s[col0], bb1 = b1_s[col1];
      int qb = nw * 256 + j * 64 + lr * 4;   // permuted byte offset of the pair
#pragma unroll
      for (int bi = 0; bi < 4; ++bi) {
        float g0 = gelu_fast(acc[mf][2 * j][bi] + bb0);
        float g1 = gelu_fast(acc[mf][2 * j + 1][bi] + bb1);
        unsigned pr = cvtpk(g0, g1);
        int hrow = mw * 32 + mf * 16 + lg * 4 + bi;
        *(unsigned*)((char*)hbuf + hrow * 1024 + (qb ^ ((hrow & 7) << 4))) = pr;
      }
    }
  }
  __syncthreads();

  // ---- GEMM2: out[128][32] = h @ W2perm^T (both sides permuted identically).
  const int rt = w >> 1, ct = w & 1;
  f32x4 acc2 = zv;
  const int row2 = rt * 16 + lr;
  for (int kb = 0; kb < 16; ++kb) {
    int cb = (kb * 64 + lg * 16) ^ ((row2 & 7) << 4);
    bfrag8 a = *(const bfrag8*)((char*)hbuf + row2 * 1024 + cb);
    bfrag8 b = *(const bfrag8*)(W2bf + (size_t)(ct * 16 + lr) * 512 + kb * 32 + lg * 8);
    acc2 = __builtin_amdgcn_mfma_f32_16x16x32_bf16(a, b, acc2, 0, 0, 0);
  }
  float b2v = b2[ct * 16 + lr];
  __syncthreads();                     // all h reads done -> safe to overlay

  float* ob = (float*)lds;             // [128][33] padded f32
#pragma unroll
  for (int bi = 0; bi < 4; ++bi)
    ob[(rt * 16 + lg * 4 + bi) * 33 + (ct * 16 + lr)] = acc2[bi] + b2v;
  __syncthreads();

  // ---- store transposed: out[b][o][m][n], 128 contiguous n per head
  const int bI = rb >> 16, mI = (rb >> 8) & 255, n0 = rb & 255;
  float* obase = out + ((size_t)(bI * 32) * 256 + mI) * 256 + n0;
#pragma unroll
  for (int p = 0; p < 4; ++p) {
    int e = tid + p * 1024;            // 0..4095
    int o = e >> 7, i = e & 127;
    obase[(size_t)o * 65536 + i] = ob[i * 33 + o];
  }
#undef STAGE
}

// ---------------- launch ------------------------------------------------------
extern "C" void kernel_launch(void* const* d_in, const int* in_sizes, int n_in,
                              void* d_out, int out_size, void* d_ws, size_t ws_size,
                              hipStream_t stream) {
  const float* rpe   = (const float*)d_in[0];
  const float* means = (const float*)d_in[1];
  const float* stds  = (const float*)d_in[2];
  const float* W1    = (const float*)d_in[3];
  const float* b1    = (const float*)d_in[4];
  const float* W2    = (const float*)d_in[5];
  const float* b2    = (const float*)d_in[6];
  float* out = (float*)d_out;

  char* ws = (char*)d_ws;
  unsigned short* W1bf = (unsigned short*)ws;             // 512*512*2 = 524288 B
  unsigned short* W2bf = (unsigned short*)(ws + 524288);  // 32*512*2  =  32768 B
  float* prm = (float*)(ws + 557056);                     // 512*2*4   =   4096 B

  prep_kernel<<<256, 256, 0, stream>>>(means, stds, W1, W2, W1bf, W2bf, prm);
  fused_kernel<<<2048, 1024, 0, stream>>>(rpe, W1bf, W2bf, prm, b1, b2, out);
}

// Round 29
// 252.561 us; speedup vs baseline: 1.2825x; 1.0072x over previous
//
#include <hip/hip_runtime.h>
#include <hip/hip_bf16.h>

typedef __attribute__((ext_vector_type(8))) short bfrag8;
typedef __attribute__((ext_vector_type(4))) float f32x4;
typedef __attribute__((ext_vector_type(4))) unsigned int u32x4;

#define IS2_SCALE 0.84932180028801907f   /* sqrt(0.5*log2(e)): exp2(-(u)^2)=exp(-t^2/2) */
#define W1_SCALE  0.46971724f            /* folds 1/(sqrt(2pi)*std) into W1 via is2 */

#if __has_builtin(__builtin_amdgcn_exp2f)
#define GEXP(x) __builtin_amdgcn_exp2f(x)
#else
__device__ __forceinline__ float gexp_asm(float x) {
  float r; asm("v_exp_f32 %0, %1" : "=v"(r) : "v"(x)); return r;
}
#define GEXP(x) gexp_asm(x)
#endif

__device__ __forceinline__ unsigned short f2bf(float x) {
  union { float f; unsigned u; } v; v.f = x;
  unsigned r = v.u + 0x7fffu + ((v.u >> 16) & 1u);
  return (unsigned short)(r >> 16);
}
__device__ __forceinline__ unsigned cvtpk(float lo, float hi) {
  unsigned r;
  asm("v_cvt_pk_bf16_f32 %0, %1, %2" : "=v"(r) : "v"(lo), "v"(hi));
  return r;
}
__device__ __forceinline__ float rcpa(float x) {
  float r; asm("v_rcp_f32 %0, %1" : "=v"(r) : "v"(x)); return r;
}
// tanh-form GELU: x/(1+exp2(x*(C0+C1*x^2)))
__device__ __forceinline__ float gelu_fast(float x) {
  float x2 = x * x;
  float w = __builtin_fmaf(x2, -0.1029488f, -2.3022078f);
  float e = GEXP(x * w);
  return x * rcpa(e + 1.0f);
}

// A-fragment pair (rows r0, r0+16) for K-block kb: 16 gaussians
__device__ __forceinline__ void gauss_frags(const f32x4* prm4, const f32x4 xa, const f32x4 xb,
                                            int kb, int lg, bfrag8* A0, bfrag8* A1) {
  const int k0 = kb * 32 + lg * 8;
  const float x0 = xa[kb >> 2], x1 = xb[kb >> 2];
  unsigned pk0[4], pk1[4];
#pragma unroll
  for (int q = 0; q < 4; ++q) {
    f32x4 P = prm4[(k0 >> 1) + q];     // {mis2_e, is2_e, mis2_o, is2_o}
    float u00 = __builtin_fmaf(x0, P[1], P[0]);
    float u01 = __builtin_fmaf(x0, P[3], P[2]);
    float u10 = __builtin_fmaf(x1, P[1], P[0]);
    float u11 = __builtin_fmaf(x1, P[3], P[2]);
    pk0[q] = cvtpk(P[1] * GEXP(-(u00 * u00)), P[3] * GEXP(-(u01 * u01)));
    pk1[q] = cvtpk(P[1] * GEXP(-(u10 * u10)), P[3] * GEXP(-(u11 * u11)));
  }
  u32x4 av0 = {pk0[0], pk0[1], pk0[2], pk0[3]};
  u32x4 av1 = {pk1[0], pk1[1], pk1[2], pk1[3]};
  *A0 = __builtin_bit_cast(bfrag8, av0);
  *A1 = __builtin_bit_cast(bfrag8, av1);
}

// ---------------- prep: weights->bf16 (W1 pre-scaled), packed gaussian params -
// W2 stored k-PERMUTED: permuted pos t in each 32-col group holds real col
// (t&1)*16 + (t>>1), matching the paired h-write layout.
__global__ void prep_kernel(const float* __restrict__ means, const float* __restrict__ stds,
                            const float* __restrict__ W1, const float* __restrict__ W2,
                            unsigned short* __restrict__ W1bf, unsigned short* __restrict__ W2bf,
                            float* __restrict__ prm /* [512][2]: mis2, is2 */) {
  int t = blockIdx.x * blockDim.x + threadIdx.x;
  int stride = gridDim.x * blockDim.x;
  for (int i = t; i < 512 * 512; i += stride) W1bf[i] = f2bf(W1[i] * W1_SCALE);
  for (int i = t; i < 32 * 512; i += stride) {
    int q = i & 511;
    int c = (q & ~31) | ((q & 1) << 4) | ((q & 31) >> 1);   // inverse permutation
    W2bf[i] = f2bf(W2[(i & ~511) | c]);
  }
  for (int i = t; i < 512; i += stride) {
    float s = fabsf(stds[i]) + 0.01f;
    float is2 = (1.0f / s) * IS2_SCALE;
    prm[2 * i] = -means[i] * is2;        // mis2
    prm[2 * i + 1] = is2;                // is2  (coef folded into W1)
  }
}

// ---------------- fused main kernel ------------------------------------------
// 1024 threads = 16 waves (4M x 4N), 128 rows/block, BK=32, triple-buffered B,
// ONE barrier per kb, half-split pipeline, per-SIMD gaussian producer waves,
// paired permuted h-writes (R25 base, 254.4 us). NEW: GEMM2 results stored
// DIRECTLY to global as float4 (lane's 4 C-values are consecutive n) — deletes
// the ob[128][33] LDS round-trip and two tail barriers per round.
__global__ __launch_bounds__(1024, 4) void fused_kernel(
    const float* __restrict__ rpe, const unsigned short* __restrict__ W1bf,
    const unsigned short* __restrict__ W2bf, const float* __restrict__ prm,
    const float* __restrict__ b1, const float* __restrict__ b2,
    float* __restrict__ out) {
  __shared__ __attribute__((aligned(16))) char lds[131072 + 4096 + 2048 + 2048];
  // [0,96K): 3x32KB B buffers; [96K,120K): gsl 3x8KB; h[128][512] overlays [0,128K)
  char*  gsl   = lds + 98304;                             // [3][4mw][2fr][4lg][16lr]x16B
  float* prm_s = (float*)(lds + 131072);                  // [512][2] = 4KB
  float* rpe_s = (float*)(lds + 131072 + 4096);           // [128][4] = 2KB
  float* b1_s  = (float*)(lds + 131072 + 4096 + 2048);    // [512]    = 2KB

  const int tid = threadIdx.x;
  const int rb = blockIdx.x * 128;

  if (tid < 512) rpe_s[tid] = rpe[rb * 4 + tid];
  prm_s[tid] = prm[tid];                 // 1024 floats
  if (tid < 512) b1_s[tid] = b1[tid];

  int goff[2];
#pragma unroll
  for (int i = 0; i < 2; ++i) {
    int c = i * 1024 + tid;
    int j = ((c >> 6) << 4) + (c & 15);
    goff[i] = j * 512 + ((c >> 4) & 3) * 8;
  }
  const char* Wc = (const char*)W1bf;

#define STAGE(buf, kb)                                                          \
  {                                                                             \
    _Pragma("unroll") for (int i_ = 0; i_ < 2; ++i_) {                          \
      const void* gp = (const void*)(Wc + (size_t)goff[i_] * 2 + (kb) * 64);    \
      void* lp = (void*)(lds + (buf) * 32768 + i_ * 16384 + tid * 16);          \
      __builtin_amdgcn_global_load_lds(                                         \
          (const __attribute__((address_space(1))) void*)gp,                    \
          (__attribute__((address_space(3))) void*)lp, 16, 0, 0);               \
    }                                                                           \
  }

  STAGE(0, 0);
  STAGE(1, 1);

  const int w = tid >> 6, l = tid & 63;
  const int lr = l & 15, lg = l >> 4;
  const int mw = w >> 2, nw = w & 3;     // 4 M-waves x 4 N-waves
  const int r0 = mw * 32 + lr;           // A rows r0 and r0+16
  const bool prod = (mw == nw);          // waves 0,5,10,15 -> one per SIMD

  const f32x4 xa = *(const f32x4*)&rpe_s[r0 * 4];
  const f32x4 xb = *(const f32x4*)&rpe_s[(r0 + 16) * 4];
  const f32x4* prm4 = (const f32x4*)prm_s;

  char* gbase = gsl + mw * 2048 + lg * 256 + lr * 16;   // + slot*8192, frag1 +1024

  __syncthreads();   // rpe/prm/b1 staged (needed by producers below); B 0,1 in flight

  // ---- prologue: producers fill slots 0,1
  if (prod) {
    bfrag8 t0, t1;
    gauss_frags(prm4, xa, xb, 0, lg, &t0, &t1);
    *(bfrag8*)(gbase) = t0;  *(bfrag8*)(gbase + 1024) = t1;
    gauss_frags(prm4, xa, xb, 1, lg, &t0, &t1);
    *(bfrag8*)(gbase + 8192) = t0;  *(bfrag8*)(gbase + 8192 + 1024) = t1;
  }
  __syncthreads();   // gsl slots 0,1 visible; B slices 0,1 drained (vmcnt in syncthreads)

  f32x4 zv = {0.f, 0.f, 0.f, 0.f};
  f32x4 acc[2][8];
#pragma unroll
  for (int mf = 0; mf < 2; ++mf)
#pragma unroll
    for (int nf = 0; nf < 8; ++nf) acc[mf][nf] = zv;

  // ---- pre-read A(0) + B(0, half0)
  bfrag8 acur0 = *(const bfrag8*)(gbase);
  bfrag8 acur1 = *(const bfrag8*)(gbase + 1024);
  bfrag8 fA[4], fB[4];
  {
    const char* Bb = lds + nw * 8192 + lg * 256 + lr * 16;
#pragma unroll
    for (int nf = 0; nf < 4; ++nf) fA[nf] = *(const bfrag8*)(Bb + nf * 1024);
  }

#pragma unroll
  for (int kb = 0; kb < 16; ++kb) {
    // certify buf(kb+1) (stage issued iter kb-1) + gsl slot(kb+1) writes.
    // vmcnt(0) is REQUIRED (hf1 read-ahead depends on buf kb+1 complete).
    asm volatile("s_waitcnt vmcnt(0)" ::: "memory");
    __builtin_amdgcn_s_barrier();
    __builtin_amdgcn_sched_barrier(0);
    if (kb < 14) STAGE((kb + 2) % 3, kb + 2);

    // ---- hf0: issue reads half1, MFMA half0
    const char* Bb = lds + (kb % 3) * 32768 + nw * 8192 + lg * 256 + lr * 16;
    __builtin_amdgcn_s_setprio(1);
#pragma unroll
    for (int nf = 0; nf < 4; ++nf) fB[nf] = *(const bfrag8*)(Bb + (nf + 4) * 1024);
#pragma unroll
    for (int nf = 0; nf < 4; ++nf) {
      acc[0][nf] = __builtin_amdgcn_mfma_f32_16x16x32_bf16(acur0, fA[nf], acc[0][nf], 0, 0, 0);
      acc[1][nf] = __builtin_amdgcn_mfma_f32_16x16x32_bf16(acur1, fA[nf], acc[1][nf], 0, 0, 0);
    }
    __builtin_amdgcn_s_setprio(0);
    __builtin_amdgcn_sched_barrier(0);

    // ---- hf1: read-ahead B(kb+1, half0), MFMA half1
    __builtin_amdgcn_s_setprio(1);
    if (kb < 15) {
      const char* Bn = lds + ((kb + 1) % 3) * 32768 + nw * 8192 + lg * 256 + lr * 16;
#pragma unroll
      for (int nf = 0; nf < 4; ++nf) fA[nf] = *(const bfrag8*)(Bn + nf * 1024);
    }
#pragma unroll
    for (int nf = 0; nf < 4; ++nf) {
      acc[0][nf + 4] = __builtin_amdgcn_mfma_f32_16x16x32_bf16(acur0, fB[nf], acc[0][nf + 4], 0, 0, 0);
      acc[1][nf + 4] = __builtin_amdgcn_mfma_f32_16x16x32_bf16(acur1, fB[nf], acc[1][nf + 4], 0, 0, 0);
    }
    __builtin_amdgcn_s_setprio(0);

    // ---- A pipeline: read a(kb+1) from slot (kb+1)%3 (written iter kb-1)
    if (kb < 15) {
      const char* gs = gbase + ((kb + 1) % 3) * 8192;
      acur0 = *(const bfrag8*)(gs);
      acur1 = *(const bfrag8*)(gs + 1024);
    }
    // ---- producer: gauss(kb+2) -> slot (kb+2)%3, drained before next barrier
    if (prod && kb < 14) {
      bfrag8 t0, t1;
      gauss_frags(prm4, xa, xb, kb + 2, lg, &t0, &t1);
      char* gd = gbase + ((kb + 2) % 3) * 8192;
      *(bfrag8*)(gd) = t0;  *(bfrag8*)(gd + 1024) = t1;
      asm volatile("s_waitcnt lgkmcnt(0)" ::: "memory");
    }
    __builtin_amdgcn_sched_barrier(0);
  }
  __syncthreads();   // all B/gsl reads done -> safe to overlay h

  // ---- bias + fast GELU -> h in LDS [128][512-permuted] bf16, XOR-swizzled,
  //      one aligned b32 write per cvtpk pair (cols c, c+16 adjacent under pi)
  unsigned short* hbuf = (unsigned short*)lds;
#pragma unroll
  for (int mf = 0; mf < 2; ++mf) {
#pragma unroll
    for (int j = 0; j < 4; ++j) {        // nf pair (2j, 2j+1)
      int col0 = nw * 128 + j * 32 + lr;
      int col1 = col0 + 16;
      float bb0 = b1_s[col0], bb1 = b1_s[col1];
      int qb = nw * 256 + j * 64 + lr * 4;   // permuted byte offset of the pair
#pragma unroll
      for (int bi = 0; bi < 4; ++bi) {
        float g0 = gelu_fast(acc[mf][2 * j][bi] + bb0);
        float g1 = gelu_fast(acc[mf][2 * j + 1][bi] + bb1);
        unsigned pr = cvtpk(g0, g1);
        int hrow = mw * 32 + mf * 16 + lg * 4 + bi;
        *(unsigned*)((char*)hbuf + hrow * 1024 + (qb ^ ((hrow & 7) << 4))) = pr;
      }
    }
  }
  __syncthreads();

  // ---- GEMM2: out[128][32] = h @ W2perm^T. 16 waves: 8(row) x 2(col) tiles.
  const int rt = w >> 1, ct = w & 1;
  f32x4 acc2 = zv;
  const int row2 = rt * 16 + lr;
  for (int kb = 0; kb < 16; ++kb) {
    int cb = (kb * 64 + lg * 16) ^ ((row2 & 7) << 4);
    bfrag8 a = *(const bfrag8*)((char*)hbuf + row2 * 1024 + cb);
    bfrag8 b = *(const bfrag8*)(W2bf + (size_t)(ct * 16 + lr) * 512 + kb * 32 + lg * 8);
    acc2 = __builtin_amdgcn_mfma_f32_16x16x32_bf16(a, b, acc2, 0, 0, 0);
  }
  float b2v = b2[ct * 16 + lr];

  // ---- DIRECT store: C layout col=lane&15 (o), row=lg*4+bi -> lane's 4 values
  // are consecutive n of out[b][o][m][n]. One aligned float4 store, no LDS.
  {
    const int bI = rb >> 16, mI = (rb >> 8) & 255, n0 = rb & 255;
    f32x4 v = {acc2[0] + b2v, acc2[1] + b2v, acc2[2] + b2v, acc2[3] + b2v};
    size_t off = ((size_t)(bI * 32 + ct * 16 + lr) * 256 + mI) * 256
               + n0 + rt * 16 + lg * 4;
    *reinterpret_cast<f32x4*>(out + off) = v;
  }
#undef STAGE
}

// ---------------- launch ------------------------------------------------------
extern "C" void kernel_launch(void* const* d_in, const int* in_sizes, int n_in,
                              void* d_out, int out_size, void* d_ws, size_t ws_size,
                              hipStream_t stream) {
  const float* rpe   = (const float*)d_in[0];
  const float* means = (const float*)d_in[1];
  const float* stds  = (const float*)d_in[2];
  const float* W1    = (const float*)d_in[3];
  const float* b1    = (const float*)d_in[4];
  const float* W2    = (const float*)d_in[5];
  const float* b2    = (const float*)d_in[6];
  float* out = (float*)d_out;

  char* ws = (char*)d_ws;
  unsigned short* W1bf = (unsigned short*)ws;             // 512*512*2 = 524288 B
  unsigned short* W2bf = (unsigned short*)(ws + 524288);  // 32*512*2  =  32768 B
  float* prm = (float*)(ws + 557056);                     // 512*2*4   =   4096 B

  prep_kernel<<<256, 256, 0, stream>>>(means, stds, W1, W2, W1bf, W2bf, prm);
  fused_kernel<<<2048, 1024, 0, stream>>>(rpe, W1bf, W2bf, prm, b1, b2, out);
}